// Round 10
// baseline (493.003 us; speedup 1.0000x reference)
//
#include <hip/hip_runtime.h>
#include <hip/hip_cooperative_groups.h>
#include <math.h>

namespace cg = cooperative_groups;

// Problem constants
#define B_ 256
#define M_ 512
#define D_ 768
#define H_ 8
#define DH_ 96
#define C_ 768

typedef float  f32x4_t __attribute__((ext_vector_type(4)));
typedef short  s16x8   __attribute__((ext_vector_type(8)));
typedef unsigned short u16;

__device__ __forceinline__ u16 cvt_bf16(float f) {
    union { float f; unsigned int u; } v; v.f = f;
    unsigned int r = (v.u + 0x7FFFu + ((v.u >> 16) & 1u)) >> 16;
    return (u16)r;
}
__device__ __forceinline__ float bf16_f32(u16 h) {
    union { unsigned int u; float f; } v; v.u = ((unsigned int)h) << 16;
    return v.f;
}

#define ACC_INIT {{0,0,0,0},{0,0,0,0},{0,0,0,0},{0,0,0,0}}
#define SCALE_ 0.10206207261596577f   // 1/sqrt(96)

struct P {
    const float *cs, *wdta, *mem, *ipw, *ipb, *outw, *outb;
    const float *rw, *rb, *www_w, *www_b, *ew, *eb, *ugw, *ugb, *fgw, *fgb;
    u16 *memb, *csb, *ipwb, *rwb, *wwwb, *ewb, *outwb;
    u16 *khb, *vhT, *rwkeysb, *qrwb, *E, *ctxb;
    float *erase, *vg, *gc, *delta, *wwb, *rd_out, *mem_out;
};

// ---------------------------------------------------------------------------
// 64x64 bf16 MFMA GEMM core (proven R5): tile = A(64xK) @ B(64xK)^T.
// ---------------------------------------------------------------------------
template<int BK>
__device__ __forceinline__ void mm64b(
    const u16* __restrict__ A, int lda, const u16* __restrict__ B, int ldb,
    int ksteps, int bRowClamp, u16* lA, u16* lB, f32x4_t* acc, int nfrag)
{
    constexpr int NL = BK / 32;
    const int t = threadIdx.x;
    const int srow = t >> 2, kq = t & 3;
    const int l = t & 63, w = t >> 6;
    const int brow = srow < bRowClamp ? srow : bRowClamp;

    for (int ks = 0; ks < ksteps; ++ks) {
        s16x8 va[NL], vb[NL];
        #pragma unroll
        for (int c = 0; c < NL; ++c) {
            const int ko = ks * BK + (kq * NL + c) * 8;
            va[c] = *reinterpret_cast<const s16x8*>(A + (size_t)srow * lda + ko);
            vb[c] = *reinterpret_cast<const s16x8*>(B + (size_t)brow * ldb + ko);
        }
        __syncthreads();
        #pragma unroll
        for (int c = 0; c < NL; ++c) {
            const int kb = kq * NL + c;
            *reinterpret_cast<s16x8*>(lA + (kb * 64 + srow) * 8) = va[c];
            *reinterpret_cast<s16x8*>(lB + (kb * 64 + srow) * 8) = vb[c];
        }
        __syncthreads();
        #pragma unroll
        for (int ksub = 0; ksub < NL; ++ksub) {
            const int kb = (l >> 4) + ksub * 4;
            s16x8 af = *reinterpret_cast<const s16x8*>(lA + (kb * 64 + w * 16 + (l & 15)) * 8);
            #pragma unroll
            for (int nb = 0; nb < 4; ++nb) {
                if (nb < nfrag) {
                    s16x8 bf = *reinterpret_cast<const s16x8*>(lB + (kb * 64 + nb * 16 + (l & 15)) * 8);
                    acc[nb] = __builtin_amdgcn_mfma_f32_16x16x32_bf16(af, bf, acc[nb], 0, 0, 0);
                }
            }
        }
    }
}

// C/D layout: col = lane&15, row = (lane>>4)*4 + reg (within wave's 16-row slice).
__device__ __forceinline__ void epilogue_f32(
    const f32x4_t* acc, float* out, int ldo, int m0, int n0,
    const float* bias, int act, int nfrag)
{
    const int t = threadIdx.x, l = t & 63, w = t >> 6;
    const int mbase = m0 + w * 16 + (l >> 4) * 4;
    #pragma unroll
    for (int nb = 0; nb < 4; ++nb) {
        if (nb >= nfrag) break;
        const int col = n0 + nb * 16 + (l & 15);
        const float bv = bias ? bias[col] : 0.0f;
        #pragma unroll
        for (int r = 0; r < 4; ++r) {
            float v = acc[nb][r] + bv;
            if (act) v = 1.0f / (1.0f + expf(-v));
            out[(size_t)(mbase + r) * ldo + col] = v;
        }
    }
}

__device__ __forceinline__ void epilogue_bf16(
    const f32x4_t* acc, u16* out, int ldo, int m0, int n0,
    const float* bias, int nfrag)
{
    const int t = threadIdx.x, l = t & 63, w = t >> 6;
    const int mbase = m0 + w * 16 + (l >> 4) * 4;
    #pragma unroll
    for (int nb = 0; nb < 4; ++nb) {
        if (nb >= nfrag) break;
        const int col = n0 + nb * 16 + (l & 15);
        const float bv = bias ? bias[col] : 0.0f;
        #pragma unroll
        for (int r = 0; r < 4; ++r)
            out[(size_t)(mbase + r) * ldo + col] = cvt_bf16(acc[nb][r] + bv);
    }
}

// ---------------------------------------------------------------------------
// Phase bodies (shared between cooperative mega-kernel and fallback launches)
// ---------------------------------------------------------------------------

// Phase 0: conv (2304 units) + vg/gc GEMV (24 units) = 2328
__device__ __forceinline__ void conv_body(const P& p, int bid, int t, float* sred)
{
    if (bid < 2304) {
        const float* src; u16* dst; int base;
        if      (bid < 192)  { src = p.mem;   dst = p.memb;  base = bid; }
        else if (bid < 288)  { src = p.cs;    dst = p.csb;   base = bid - 192; }
        else if (bid < 1152) { src = p.ipw;   dst = p.ipwb;  base = bid - 288; }
        else if (bid < 1440) { src = p.rw;    dst = p.rwb;   base = bid - 1152; }
        else if (bid < 1728) { src = p.www_w; dst = p.wwwb;  base = bid - 1440; }
        else if (bid < 2016) { src = p.ew;    dst = p.ewb;   base = bid - 1728; }
        else                 { src = p.outw;  dst = p.outwb; base = bid - 2016; }
        const size_t i = ((size_t)base * 256 + t) * 8;
        float4 x = *reinterpret_cast<const float4*>(src + i);
        float4 y = *reinterpret_cast<const float4*>(src + i + 4);
        s16x8 o;
        o[0]=cvt_bf16(x.x); o[1]=cvt_bf16(x.y); o[2]=cvt_bf16(x.z); o[3]=cvt_bf16(x.w);
        o[4]=cvt_bf16(y.x); o[5]=cvt_bf16(y.y); o[6]=cvt_bf16(y.z); o[7]=cvt_bf16(y.w);
        *reinterpret_cast<s16x8*>(dst + i) = o;
    } else {
        const int lid = bid - 2304;
        const int v = lid / 12, kt = lid % 12;
        const float* gw = v == 0 ? p.ugw : p.fgw;
        const int c = t & 63, g = t >> 6;
        const int col = kt * 64 + c;
        float acc = 0.f;
        #pragma unroll 4
        for (int i = 0; i < 192; ++i) {
            const int row = g * 192 + i;
            acc += p.outw[(size_t)row * 768 + col] * gw[768 + row];
        }
        sred[t] = acc;
        __syncthreads();
        if (g == 0)
            p.vg[v * 768 + col] = sred[c] + sred[64 + c] + sred[128 + c] + sred[192 + c];
        if (kt == 0) {
            __syncthreads();
            float cp = p.outb[t] * gw[768 + t] + p.outb[t + 256] * gw[768 + t + 256]
                     + p.outb[t + 512] * gw[768 + t + 512];
            sred[t] = cp; __syncthreads();
            #pragma unroll
            for (int off = 128; off > 0; off >>= 1) {
                if (t < off) sred[t] += sred[t + off];
                __syncthreads();
            }
            if (t == 0) p.gc[v] = sred[0] + (v == 0 ? p.ugb[0] : p.fgb[0]);
        }
        __syncthreads();
    }
}

// Phase 1: stage1 (336 units): kh+vhT (192), rd keys (48), wr keys (48), erase (48)
__device__ __forceinline__ void stage1_body(const P& p, int bid, u16* lA, u16* lB)
{
    f32x4_t acc[4] = ACC_INIT;
    if (bid < 192) {
        const int mt = bid / 24, nt = bid % 24;
        mm64b<64>(p.memb + (size_t)mt * 64 * 768, 768,
                  p.ipwb + (size_t)768 * 768 + (size_t)nt * 64 * 768, 768,
                  12, 63, lA, lB, acc, 4);
        const int t = threadIdx.x, l = t & 63, w = t >> 6;
        const int mbase = mt * 64 + w * 16 + (l >> 4) * 4;
        if (nt < 12) {
            #pragma unroll
            for (int nb = 0; nb < 4; ++nb) {
                const int col = nt * 64 + nb * 16 + (l & 15);
                const float bv = p.ipb[768 + col];
                #pragma unroll
                for (int r = 0; r < 4; ++r)
                    p.khb[(size_t)(mbase + r) * 768 + col] = cvt_bf16(acc[nb][r] + bv);
            }
        } else {
            #pragma unroll
            for (int nb = 0; nb < 4; ++nb) {
                const int cg = (nt - 12) * 64 + nb * 16 + (l & 15);   // 0..767
                const int h = cg / 96, d = cg % 96;
                const float bv = p.ipb[1536 + cg];
                u16* dst = p.vhT + ((size_t)h * 96 + d) * 512;
                #pragma unroll
                for (int r = 0; r < 4; ++r)
                    dst[mbase + r] = cvt_bf16(acc[nb][r] + bv);
            }
        }
    } else if (bid < 240) {
        const int lid = bid - 192, mt = lid / 12, nt = lid % 12;
        mm64b<64>(p.csb + (size_t)mt * 64 * 768, 768, p.rwb + (size_t)nt * 64 * 768, 768,
                  12, 63, lA, lB, acc, 4);
        epilogue_bf16(acc, p.rwkeysb, 768, mt * 64, nt * 64, p.rb, 4);
    } else if (bid < 288) {
        const int lid = bid - 240, mt = lid / 12, nt = lid % 12;
        mm64b<64>(p.csb + (size_t)mt * 64 * 768, 768, p.wwwb + (size_t)nt * 64 * 768, 768,
                  12, 63, lA, lB, acc, 4);
        epilogue_bf16(acc, p.rwkeysb + (size_t)256 * 768, 768, mt * 64, nt * 64, p.www_b, 4);
    } else {
        const int lid = bid - 288, mt = lid / 12, nt = lid % 12;
        mm64b<64>(p.csb + (size_t)mt * 64 * 768, 768, p.ewb + (size_t)nt * 64 * 768, 768,
                  12, 63, lA, lB, acc, 4);
        epilogue_f32(acc, p.erase, 768, mt * 64, nt * 64, p.eb, 1, 4);
    }
}

// Phase 2: stage2 (96 units): qrw = rwkeys @ wq^T + bq
__device__ __forceinline__ void stage2_body(const P& p, int bid, u16* lA, u16* lB)
{
    f32x4_t acc[4] = ACC_INIT;
    const int mt = bid / 12, nt = bid % 12;
    mm64b<64>(p.rwkeysb + (size_t)mt * 64 * 768, 768, p.ipwb + (size_t)nt * 64 * 768, 768,
              12, 63, lA, lB, acc, 4);
    epilogue_bf16(acc, p.qrwb, 768, mt * 64, nt * 64, p.ipb, 4);
}

// Phase 3: scores (512 units): E[h][q][m] = exp(min(q.k*scale,30)) bf16
__device__ __forceinline__ void scores_body(const P& p, int bid, u16* lA, u16* lB)
{
    f32x4_t acc[4] = ACC_INIT;
    const int h = bid >> 6;
    const int x = bid & 63;
    const int mt = x >> 3, nt = x & 7;
    mm64b<32>(p.qrwb + (size_t)mt * 64 * 768 + h * 96, 768,
              p.khb + (size_t)nt * 64 * 768 + h * 96, 768, 3, 63, lA, lB, acc, 4);
    const int t = threadIdx.x, l = t & 63, w = t >> 6;
    const int mbase = mt * 64 + w * 16 + (l >> 4) * 4;     // q
    #pragma unroll
    for (int nb = 0; nb < 4; ++nb) {
        const int col = nt * 64 + nb * 16 + (l & 15);       // m
        #pragma unroll
        for (int r = 0; r < 4; ++r) {
            const float e = expf(fminf(acc[nb][r] * SCALE_, 30.0f));
            p.E[((size_t)h * 512 + mbase + r) * 512 + col] = cvt_bf16(e);
        }
    }
}

// Phase 4: pv (64 units): ctx = (E/rowsum) @ vhT^T
__device__ __forceinline__ void pv_body(const P& p, int bid, u16* lA, u16* lB, float* rinv)
{
    f32x4_t acc[4] = ACC_INIT;
    const int h = bid >> 3;
    const int x = bid & 7;
    const int mt = x >> 1, nt = x & 1;
    const int n0 = nt * 64;
    const int nfrag = nt == 0 ? 4 : 2;
    const int bclamp = nt == 0 ? 63 : 31;

    const u16* A  = p.E + ((size_t)h * 512 + mt * 64) * 512;
    const u16* Bv = p.vhT + ((size_t)h * 96 + n0) * 512;

    const int t = threadIdx.x;
    const int srow = t >> 2, kq = t & 3;
    const int l = t & 63, w = t >> 6;
    const int brow = srow < bclamp ? srow : bclamp;

    float rs = 0.f;
    for (int ks = 0; ks < 8; ++ks) {
        s16x8 va[2], vb[2];
        #pragma unroll
        for (int c = 0; c < 2; ++c) {
            const int ko = ks * 64 + (kq * 2 + c) * 8;
            va[c] = *reinterpret_cast<const s16x8*>(A + (size_t)srow * 512 + ko);
            vb[c] = *reinterpret_cast<const s16x8*>(Bv + (size_t)brow * 512 + ko);
        }
        #pragma unroll
        for (int c = 0; c < 2; ++c)
            #pragma unroll
            for (int j = 0; j < 8; ++j)
                rs += bf16_f32((u16)va[c][j]);
        __syncthreads();
        #pragma unroll
        for (int c = 0; c < 2; ++c) {
            const int kb = kq * 2 + c;
            *reinterpret_cast<s16x8*>(lA + (kb * 64 + srow) * 8) = va[c];
            *reinterpret_cast<s16x8*>(lB + (kb * 64 + srow) * 8) = vb[c];
        }
        __syncthreads();
        #pragma unroll
        for (int ksub = 0; ksub < 2; ++ksub) {
            const int kb = (l >> 4) + ksub * 4;
            s16x8 af = *reinterpret_cast<const s16x8*>(lA + (kb * 64 + w * 16 + (l & 15)) * 8);
            #pragma unroll
            for (int nb = 0; nb < 4; ++nb) {
                if (nb < nfrag) {
                    s16x8 bf = *reinterpret_cast<const s16x8*>(lB + (kb * 64 + nb * 16 + (l & 15)) * 8);
                    acc[nb] = __builtin_amdgcn_mfma_f32_16x16x32_bf16(af, bf, acc[nb], 0, 0, 0);
                }
            }
        }
    }
    rs += __shfl_xor(rs, 1);
    rs += __shfl_xor(rs, 2);
    if (kq == 0) rinv[srow] = 1.0f / rs;
    __syncthreads();

    const int mbase = w * 16 + (l >> 4) * 4;
    #pragma unroll
    for (int nb = 0; nb < 4; ++nb) {
        if (nb >= nfrag) break;
        const int col = n0 + nb * 16 + (l & 15);
        #pragma unroll
        for (int r = 0; r < 4; ++r) {
            const float v = acc[nb][r] * rinv[mbase + r];
            p.ctxb[(size_t)(mt * 64 + mbase + r) * 768 + h * 96 + col] = cvt_bf16(v);
        }
    }
    __syncthreads();
}

// Phase 5: finalize (560 units): [0,48) outproj; [48,304) gates+delta; [304,560) ww
__device__ __forceinline__ void finalize_body(const P& p, int bid, int t,
                                              u16* lA, u16* lB, float* red8, float* linv8)
{
    if (bid < 48) {
        f32x4_t acc[4] = ACC_INIT;
        const int mt = bid / 12, nt = bid % 12;
        mm64b<64>(p.ctxb + (size_t)mt * 64 * 768, 768, p.outwb + (size_t)nt * 64 * 768, 768,
                  12, 63, lA, lB, acc, 4);
        epilogue_f32(acc, p.rd_out, 768, mt * 64, nt * 64, p.outb, 0, 4);
    } else if (bid < 304) {
        const int b = bid - 48;
        float pu = 0.f, pf = 0.f;
        #pragma unroll
        for (int c = 0; c < 3; ++c) {
            const int i = t + c * 256;
            const float cv = p.cs[(size_t)b * 768 + i];
            const float xv = bf16_f32(p.ctxb[(size_t)b * 768 + i]);
            pu += cv * p.ugw[i] + xv * p.vg[i];
            pf += cv * p.fgw[i] + xv * p.vg[768 + i];
        }
        const int w = t >> 6, l = t & 63;
        #pragma unroll
        for (int off = 32; off > 0; off >>= 1) {
            pu += __shfl_xor(pu, off);
            pf += __shfl_xor(pf, off);
        }
        if (l == 0) { red8[w] = pu; red8[4 + w] = pf; }
        __syncthreads();
        const float ug = 1.0f / (1.0f + expf(-(red8[0] + red8[1] + red8[2] + red8[3] + p.gc[0])));
        const float fg = 1.0f / (1.0f + expf(-(red8[4] + red8[5] + red8[6] + red8[7] + p.gc[1])));
        #pragma unroll
        for (int c = 0; c < 3; ++c) {
            const int i = t + c * 256;
            p.delta[(size_t)b * 768 + i] = p.wdta[(size_t)b * 768 + i] * ug
                                         - p.erase[(size_t)b * 768 + i] * fg;
        }
        __syncthreads();
    } else {
        const int b = bid - 304;
        const int w = t >> 6, l = t & 63;
        #pragma unroll
        for (int hh = 0; hh < 2; ++hh) {
            const int h = w * 2 + hh;
            const u16* row = p.E + ((size_t)h * 512 + 256 + b) * 512;
            float s = 0.f;
            #pragma unroll
            for (int c = 0; c < 8; ++c) s += bf16_f32(row[c * 64 + l]);
            #pragma unroll
            for (int off = 32; off > 0; off >>= 1) s += __shfl_xor(s, off);
            if (l == 0) linv8[h] = 1.0f / s;
        }
        __syncthreads();
        #pragma unroll
        for (int mm_ = 0; mm_ < 2; ++mm_) {
            const int m = t + mm_ * 256;
            float s = 0.f;
            #pragma unroll
            for (int h = 0; h < H_; ++h)
                s += bf16_f32(p.E[((size_t)h * 512 + 256 + b) * 512 + m]) * linv8[h];
            p.wwb[(size_t)b * 512 + m] = s * 0.125f;
        }
        __syncthreads();
    }
}

// Phase 6: update (16384 units of 8 m-rows): out = mem + ww*delta, NT stores.
__device__ __forceinline__ void update_body(const P& p, int u, int t)
{
    const int b  = u >> 6;            // 64 units per batch
    const int m0 = (u & 63) << 3;     // 8 rows
    const f32x4_t* m4 = reinterpret_cast<const f32x4_t*>(p.mem);
    f32x4_t* o4 = reinterpret_cast<f32x4_t*>(p.mem_out + (size_t)b * 393216);
    const float* drow = p.delta + (size_t)b * 768;
    #pragma unroll
    for (int ph = 0; ph < 6; ++ph) {
        const int c = t + ph * 256;           // 0..1535 = 8 rows x 192 chunks
        const int m = m0 + c / 192;
        const int d4 = c % 192;
        const float w = p.wwb[(size_t)b * 512 + m];
        const f32x4_t dd = *reinterpret_cast<const f32x4_t*>(drow + d4 * 4);
        f32x4_t mm = m4[(size_t)m * 192 + d4];
        f32x4_t r = mm + w * dd;
        __builtin_nontemporal_store(r, &o4[(size_t)m * 192 + d4]);
    }
}

// ---------------------------------------------------------------------------
// Cooperative mega-kernel: 512 blocks x 256 threads, 2 blocks/CU guaranteed.
// ---------------------------------------------------------------------------
__global__ __launch_bounds__(256, 2) void mega_kernel(P p)
{
    cg::grid_group grid = cg::this_grid();
    __shared__ u16 lA[8192], lB[8192];
    __shared__ float sred[256];
    __shared__ float rinv[64];
    __shared__ float red8[8];
    __shared__ float linv8[8];
    const int bid = blockIdx.x, t = threadIdx.x;

    for (int u = bid; u < 2328; u += 512) conv_body(p, u, t, sred);
    grid.sync();
    if (bid < 336) stage1_body(p, bid, lA, lB);
    grid.sync();
    if (bid < 96) stage2_body(p, bid, lA, lB);
    grid.sync();
    scores_body(p, bid, lA, lB);
    grid.sync();
    if (bid < 64) pv_body(p, bid, lA, lB, rinv);
    grid.sync();
    for (int u = bid; u < 560; u += 512) finalize_body(p, u, t, lA, lB, red8, linv8);
    grid.sync();
    for (int u = bid; u < 16384; u += 512) update_body(p, u, t);
}

// ---------------------------------------------------------------------------
// Fallback wrappers (identical bodies, 7 launches) — used if coop launch fails.
// ---------------------------------------------------------------------------
__global__ __launch_bounds__(256) void k_conv(P p) {
    __shared__ float sred[256];
    conv_body(p, blockIdx.x, threadIdx.x, sred);
}
__global__ __launch_bounds__(256) void k_stage1(P p) {
    __shared__ u16 lA[8192], lB[8192];
    stage1_body(p, blockIdx.x, lA, lB);
}
__global__ __launch_bounds__(256) void k_stage2(P p) {
    __shared__ u16 lA[8192], lB[8192];
    stage2_body(p, blockIdx.x, lA, lB);
}
__global__ __launch_bounds__(256) void k_scores(P p) {
    __shared__ u16 lA[2048], lB[2048];
    scores_body(p, blockIdx.x, lA, lB);
}
__global__ __launch_bounds__(256) void k_pv(P p) {
    __shared__ u16 lA[8192], lB[8192];
    __shared__ float rinv[64];
    pv_body(p, blockIdx.x, lA, lB, rinv);
}
__global__ __launch_bounds__(256) void k_finalize(P p) {
    __shared__ u16 lA[8192], lB[8192];
    __shared__ float red8[8], linv8[8];
    finalize_body(p, blockIdx.x, threadIdx.x, lA, lB, red8, linv8);
}
__global__ __launch_bounds__(256) void k_update(P p) {
    update_body(p, blockIdx.x, threadIdx.x);
}

// ---------------------------------------------------------------------------
extern "C" void kernel_launch(void* const* d_in, const int* in_sizes, int n_in,
                              void* d_out, int out_size, void* d_ws, size_t ws_size,
                              hipStream_t stream)
{
    P p;
    p.cs    = (const float*)d_in[0];
    p.wdta  = (const float*)d_in[1];
    p.mem   = (const float*)d_in[2];
    p.ipw   = (const float*)d_in[3];
    p.ipb   = (const float*)d_in[4];
    p.outw  = (const float*)d_in[5];
    p.outb  = (const float*)d_in[6];
    p.rw    = (const float*)d_in[7];
    p.rb    = (const float*)d_in[8];
    p.www_w = (const float*)d_in[9];
    p.www_b = (const float*)d_in[10];
    p.ew    = (const float*)d_in[11];
    p.eb    = (const float*)d_in[12];
    p.ugw   = (const float*)d_in[13];
    p.ugb   = (const float*)d_in[14];
    p.fgw   = (const float*)d_in[15];
    p.fgb   = (const float*)d_in[16];

    p.rd_out  = (float*)d_out;                 // read_data (B, D)
    p.mem_out = (float*)d_out + B_ * D_;       // updated_memory (B, M, D)

    // Scratch in mem_out region (dead until update phase; update reads only
    // inputs + d_ws). Offsets in f32 WORDS, all %4==0. (R9 layout, verified.)
    float* S0 = p.mem_out;
    p.memb    = (u16*)(S0 + 0);         // 512*768 bf16
    p.csb     = (u16*)(S0 + 196608);    // 256*768 bf16
    p.ipwb    = (u16*)(S0 + 294912);    // 2304*768 bf16
    p.rwb     = (u16*)(S0 + 1179648);   // 768*768 bf16
    p.wwwb    = (u16*)(S0 + 1474560);   // 768*768 bf16
    p.ewb     = (u16*)(S0 + 1769472);   // 768*768 bf16
    p.outwb   = (u16*)(S0 + 2064384);   // 768*768 bf16
    p.khb     = (u16*)(S0 + 2359296);   // 512*768 bf16
    p.vhT     = (u16*)(S0 + 2555904);   // 768*512 bf16
    p.rwkeysb = (u16*)(S0 + 2752512);   // 512*768 bf16
    p.qrwb    = (u16*)(S0 + 2949120);   // 512*768 bf16 (end 3145728 f)

    // d_ws (f32 words; all offsets %4==0):
    float* ws = (float*)d_ws;
    p.erase = ws;                       // 196608 @ 0
    p.ctxb  = (u16*)(ws + 196608);      //  98304
    p.E     = (u16*)(ws + 294912);      // 1048576
    p.vg    = ws + 1343488;             //   1536
    p.gc    = ws + 1345024;             //     16
    p.delta = ws + 1345040;             // 196608
    p.wwb   = ws + 1541648;             // 131072 (end 1672720 f = 6.7 MB)

    void* args[] = { &p };
    hipError_t err = hipLaunchCooperativeKernel((const void*)mega_kernel,
                                                dim3(512), dim3(256), args, 0, stream);
    if (err != hipSuccess) {
        (void)hipGetLastError();   // clear error, fall back to 7-launch chain
        k_conv<<<2328, 256, 0, stream>>>(p);
        k_stage1<<<336, 256, 0, stream>>>(p);
        k_stage2<<<96, 256, 0, stream>>>(p);
        k_scores<<<512, 256, 0, stream>>>(p);
        k_pv<<<64, 256, 0, stream>>>(p);
        k_finalize<<<560, 256, 0, stream>>>(p);
        k_update<<<16384, 256, 0, stream>>>(p);
    }
}

// Round 11
// 141.144 us; speedup vs baseline: 3.4929x; 3.4929x over previous
//
#include <hip/hip_runtime.h>
#include <math.h>

// Problem constants
#define B_ 256
#define M_ 512
#define D_ 768
#define H_ 8
#define DH_ 96
#define C_ 768

typedef float  f32x4_t __attribute__((ext_vector_type(4)));
typedef short  s16x8   __attribute__((ext_vector_type(8)));
typedef unsigned short u16;

__device__ __forceinline__ u16 cvt_bf16(float f) {
    union { float f; unsigned int u; } v; v.f = f;
    unsigned int r = (v.u + 0x7FFFu + ((v.u >> 16) & 1u)) >> 16;
    return (u16)r;
}
__device__ __forceinline__ float bf16_f32(u16 h) {
    union { unsigned int u; float f; } v; v.u = ((unsigned int)h) << 16;
    return v.f;
}

#define ACC_INIT {{0,0,0,0},{0,0,0,0},{0,0,0,0},{0,0,0,0}}
#define SCALE_ 0.10206207261596577f   // 1/sqrt(96)

// ---------------------------------------------------------------------------
// 64x64 bf16 MFMA GEMM core (proven R5/R9): tile = A(64xK) @ B(64xK)^T.
// ---------------------------------------------------------------------------
template<int BK>
__device__ __forceinline__ void mm64b(
    const u16* __restrict__ A, int lda, const u16* __restrict__ B, int ldb,
    int ksteps, int bRowClamp, u16* lA, u16* lB, f32x4_t* acc, int nfrag)
{
    constexpr int NL = BK / 32;
    const int t = threadIdx.x;
    const int srow = t >> 2, kq = t & 3;
    const int l = t & 63, w = t >> 6;
    const int brow = srow < bRowClamp ? srow : bRowClamp;

    for (int ks = 0; ks < ksteps; ++ks) {
        s16x8 va[NL], vb[NL];
        #pragma unroll
        for (int c = 0; c < NL; ++c) {
            const int ko = ks * BK + (kq * NL + c) * 8;
            va[c] = *reinterpret_cast<const s16x8*>(A + (size_t)srow * lda + ko);
            vb[c] = *reinterpret_cast<const s16x8*>(B + (size_t)brow * ldb + ko);
        }
        __syncthreads();
        #pragma unroll
        for (int c = 0; c < NL; ++c) {
            const int kb = kq * NL + c;
            *reinterpret_cast<s16x8*>(lA + (kb * 64 + srow) * 8) = va[c];
            *reinterpret_cast<s16x8*>(lB + (kb * 64 + srow) * 8) = vb[c];
        }
        __syncthreads();
        #pragma unroll
        for (int ksub = 0; ksub < NL; ++ksub) {
            const int kb = (l >> 4) + ksub * 4;
            s16x8 af = *reinterpret_cast<const s16x8*>(lA + (kb * 64 + w * 16 + (l & 15)) * 8);
            #pragma unroll
            for (int nb = 0; nb < 4; ++nb) {
                if (nb < nfrag) {
                    s16x8 bf = *reinterpret_cast<const s16x8*>(lB + (kb * 64 + nb * 16 + (l & 15)) * 8);
                    acc[nb] = __builtin_amdgcn_mfma_f32_16x16x32_bf16(af, bf, acc[nb], 0, 0, 0);
                }
            }
        }
    }
}

// C/D layout: col = lane&15, row = (lane>>4)*4 + reg (within wave's 16-row slice).
__device__ __forceinline__ void epilogue_f32(
    const f32x4_t* acc, float* out, int ldo, int m0, int n0,
    const float* bias, int act, int nfrag)
{
    const int t = threadIdx.x, l = t & 63, w = t >> 6;
    const int mbase = m0 + w * 16 + (l >> 4) * 4;
    #pragma unroll
    for (int nb = 0; nb < 4; ++nb) {
        if (nb >= nfrag) break;
        const int col = n0 + nb * 16 + (l & 15);
        const float bv = bias ? bias[col] : 0.0f;
        #pragma unroll
        for (int r = 0; r < 4; ++r) {
            float v = acc[nb][r] + bv;
            if (act) v = 1.0f / (1.0f + expf(-v));
            out[(size_t)(mbase + r) * ldo + col] = v;
        }
    }
}

__device__ __forceinline__ void epilogue_bf16(
    const f32x4_t* acc, u16* out, int ldo, int m0, int n0,
    const float* bias, int nfrag)
{
    const int t = threadIdx.x, l = t & 63, w = t >> 6;
    const int mbase = m0 + w * 16 + (l >> 4) * 4;
    #pragma unroll
    for (int nb = 0; nb < 4; ++nb) {
        if (nb >= nfrag) break;
        const int col = n0 + nb * 16 + (l & 15);
        const float bv = bias ? bias[col] : 0.0f;
        #pragma unroll
        for (int r = 0; r < 4; ++r)
            out[(size_t)(mbase + r) * ldo + col] = cvt_bf16(acc[nb][r] + bv);
    }
}

// ---------------------------------------------------------------------------
// L1 conv (2328 blocks): f32->bf16 conversions (2304) + vg/gc GEMV (24).
// ---------------------------------------------------------------------------
__global__ __launch_bounds__(256) void conv_kernel(
    const float* __restrict__ mem, const float* __restrict__ cs,
    const float* __restrict__ ipw, const float* __restrict__ rw,
    const float* __restrict__ www, const float* __restrict__ ew,
    const float* __restrict__ outw, const float* __restrict__ outb,
    const float* __restrict__ ugw, const float* __restrict__ ugb,
    const float* __restrict__ fgw, const float* __restrict__ fgb,
    u16* __restrict__ memb, u16* __restrict__ csb, u16* __restrict__ ipwb,
    u16* __restrict__ rwb, u16* __restrict__ wwwb, u16* __restrict__ ewb,
    u16* __restrict__ outwb, float* __restrict__ vg, float* __restrict__ gc)
{
    __shared__ float sred[256];
    const int bid = blockIdx.x, t = threadIdx.x;

    if (bid < 2304) {
        const float* src; u16* dst; int base;
        if      (bid < 192)  { src = mem;  dst = memb;  base = bid; }
        else if (bid < 288)  { src = cs;   dst = csb;   base = bid - 192; }
        else if (bid < 1152) { src = ipw;  dst = ipwb;  base = bid - 288; }
        else if (bid < 1440) { src = rw;   dst = rwb;   base = bid - 1152; }
        else if (bid < 1728) { src = www;  dst = wwwb;  base = bid - 1440; }
        else if (bid < 2016) { src = ew;   dst = ewb;   base = bid - 1728; }
        else                 { src = outw; dst = outwb; base = bid - 2016; }
        const size_t i = ((size_t)base * 256 + t) * 8;
        float4 x = *reinterpret_cast<const float4*>(src + i);
        float4 y = *reinterpret_cast<const float4*>(src + i + 4);
        s16x8 o;
        o[0]=cvt_bf16(x.x); o[1]=cvt_bf16(x.y); o[2]=cvt_bf16(x.z); o[3]=cvt_bf16(x.w);
        o[4]=cvt_bf16(y.x); o[5]=cvt_bf16(y.y); o[6]=cvt_bf16(y.z); o[7]=cvt_bf16(y.w);
        *reinterpret_cast<s16x8*>(dst + i) = o;
    } else {
        const int lid = bid - 2304;
        const int v = lid / 12, kt = lid % 12;
        const float* gw = v == 0 ? ugw : fgw;
        const int c = t & 63, g = t >> 6;
        const int col = kt * 64 + c;
        float acc = 0.f;
        #pragma unroll 4
        for (int i = 0; i < 192; ++i) {
            const int row = g * 192 + i;
            acc += outw[(size_t)row * 768 + col] * gw[768 + row];
        }
        sred[t] = acc;
        __syncthreads();
        if (g == 0)
            vg[v * 768 + col] = sred[c] + sred[64 + c] + sred[128 + c] + sred[192 + c];
        if (kt == 0) {
            __syncthreads();
            float cp = outb[t] * gw[768 + t] + outb[t + 256] * gw[768 + t + 256]
                     + outb[t + 512] * gw[768 + t + 512];
            sred[t] = cp; __syncthreads();
            #pragma unroll
            for (int off = 128; off > 0; off >>= 1) {
                if (t < off) sred[t] += sred[t + off];
                __syncthreads();
            }
            if (t == 0) gc[v] = sred[0] + (v == 0 ? ugb[0] : fgb[0]);
        }
    }
}

// ---------------------------------------------------------------------------
// L2 stage1 (336 blocks): kh+vhT (192), read keys (48), write keys (48), erase (48)
// ---------------------------------------------------------------------------
__global__ __launch_bounds__(256) void stage1_kernel(
    const u16* __restrict__ memb, const u16* __restrict__ csb,
    const u16* __restrict__ ipwb, const float* __restrict__ ipb,
    const u16* __restrict__ rwb, const float* __restrict__ rb,
    const u16* __restrict__ wwwb, const float* __restrict__ ww_b,
    const u16* __restrict__ ewb, const float* __restrict__ eb,
    u16* __restrict__ khb, u16* __restrict__ vhT,
    u16* __restrict__ rwkeysb, float* __restrict__ erase)
{
    __shared__ u16 lA[8192], lB[8192];
    f32x4_t acc[4] = ACC_INIT;
    const int bid = blockIdx.x;
    if (bid < 192) {
        const int mt = bid / 24, nt = bid % 24;
        mm64b<64>(memb + (size_t)mt * 64 * 768, 768,
                  ipwb + (size_t)768 * 768 + (size_t)nt * 64 * 768, 768,
                  12, 63, lA, lB, acc, 4);
        const int t = threadIdx.x, l = t & 63, w = t >> 6;
        const int mbase = mt * 64 + w * 16 + (l >> 4) * 4;
        if (nt < 12) {
            #pragma unroll
            for (int nb = 0; nb < 4; ++nb) {
                const int col = nt * 64 + nb * 16 + (l & 15);
                const float bv = ipb[768 + col];
                #pragma unroll
                for (int r = 0; r < 4; ++r)
                    khb[(size_t)(mbase + r) * 768 + col] = cvt_bf16(acc[nb][r] + bv);
            }
        } else {
            #pragma unroll
            for (int nb = 0; nb < 4; ++nb) {
                const int cg = (nt - 12) * 64 + nb * 16 + (l & 15);   // 0..767
                const int h = cg / 96, d = cg % 96;
                const float bv = ipb[1536 + cg];
                u16* dst = vhT + ((size_t)h * 96 + d) * 512;
                #pragma unroll
                for (int r = 0; r < 4; ++r)
                    dst[mbase + r] = cvt_bf16(acc[nb][r] + bv);
            }
        }
    } else if (bid < 240) {
        const int lid = bid - 192, mt = lid / 12, nt = lid % 12;
        mm64b<64>(csb + (size_t)mt * 64 * 768, 768, rwb + (size_t)nt * 64 * 768, 768,
                  12, 63, lA, lB, acc, 4);
        epilogue_bf16(acc, rwkeysb, 768, mt * 64, nt * 64, rb, 4);
    } else if (bid < 288) {
        const int lid = bid - 240, mt = lid / 12, nt = lid % 12;
        mm64b<64>(csb + (size_t)mt * 64 * 768, 768, wwwb + (size_t)nt * 64 * 768, 768,
                  12, 63, lA, lB, acc, 4);
        epilogue_bf16(acc, rwkeysb + (size_t)256 * 768, 768, mt * 64, nt * 64, ww_b, 4);
    } else {
        const int lid = bid - 288, mt = lid / 12, nt = lid % 12;
        mm64b<64>(csb + (size_t)mt * 64 * 768, 768, ewb + (size_t)nt * 64 * 768, 768,
                  12, 63, lA, lB, acc, 4);
        epilogue_f32(acc, erase, 768, mt * 64, nt * 64, eb, 1, 4);
    }
}

// ---------------------------------------------------------------------------
// L3 stage2 (96 blocks): qrw = rwkeys(512x768) @ wq^T + bq -> bf16
// ---------------------------------------------------------------------------
__global__ __launch_bounds__(256) void stage2_kernel(
    const u16* __restrict__ rwkeysb, const u16* __restrict__ ipwb,
    const float* __restrict__ ipb, u16* __restrict__ qrwb)
{
    __shared__ u16 lA[8192], lB[8192];
    f32x4_t acc[4] = ACC_INIT;
    const int mt = blockIdx.x / 12, nt = blockIdx.x % 12;
    mm64b<64>(rwkeysb + (size_t)mt * 64 * 768, 768, ipwb + (size_t)nt * 64 * 768, 768,
              12, 63, lA, lB, acc, 4);
    epilogue_bf16(acc, qrwb, 768, mt * 64, nt * 64, ipb, 4);
}

// ---------------------------------------------------------------------------
// L4 scores (grid (64,8)): E[h][q][m] = exp(min(q.k*scale,30)) bf16
// ---------------------------------------------------------------------------
__global__ __launch_bounds__(256) void scores_kernel(
    const u16* __restrict__ qrwb, const u16* __restrict__ khb, u16* __restrict__ E)
{
    __shared__ u16 lA[2048], lB[2048];
    f32x4_t acc[4] = ACC_INIT;
    const int h = blockIdx.y;
    const int mt = blockIdx.x >> 3, nt = blockIdx.x & 7;
    mm64b<32>(qrwb + (size_t)mt * 64 * 768 + h * 96, 768,
              khb + (size_t)nt * 64 * 768 + h * 96, 768, 3, 63, lA, lB, acc, 4);
    const int t = threadIdx.x, l = t & 63, w = t >> 6;
    const int mbase = mt * 64 + w * 16 + (l >> 4) * 4;     // q
    #pragma unroll
    for (int nb = 0; nb < 4; ++nb) {
        const int col = nt * 64 + nb * 16 + (l & 15);       // m
        #pragma unroll
        for (int r = 0; r < 4; ++r) {
            const float e = expf(fminf(acc[nb][r] * SCALE_, 30.0f));
            E[((size_t)h * 512 + mbase + r) * 512 + col] = cvt_bf16(e);
        }
    }
}

// ---------------------------------------------------------------------------
// L5 PV (grid (4,2,8)): ctx = (E_rows/rowsum) @ vhT^T -> ctxb bf16.
// ---------------------------------------------------------------------------
__global__ __launch_bounds__(256) void pv_kernel(
    const u16* __restrict__ E, const u16* __restrict__ vhT, u16* __restrict__ ctxb)
{
    __shared__ u16 lA[8192], lB[8192];
    __shared__ float rinv[64];
    f32x4_t acc[4] = ACC_INIT;
    const int h = blockIdx.z, mt = blockIdx.x, nt = blockIdx.y;
    const int n0 = nt * 64;
    const int nfrag = nt == 0 ? 4 : 2;
    const int bclamp = nt == 0 ? 63 : 31;

    const u16* A  = E + ((size_t)h * 512 + mt * 64) * 512;
    const u16* Bv = vhT + ((size_t)h * 96 + n0) * 512;

    const int t = threadIdx.x;
    const int srow = t >> 2, kq = t & 3;
    const int l = t & 63, w = t >> 6;
    const int brow = srow < bclamp ? srow : bclamp;

    float rs = 0.f;
    for (int ks = 0; ks < 8; ++ks) {
        s16x8 va[2], vb[2];
        #pragma unroll
        for (int c = 0; c < 2; ++c) {
            const int ko = ks * 64 + (kq * 2 + c) * 8;
            va[c] = *reinterpret_cast<const s16x8*>(A + (size_t)srow * 512 + ko);
            vb[c] = *reinterpret_cast<const s16x8*>(Bv + (size_t)brow * 512 + ko);
        }
        #pragma unroll
        for (int c = 0; c < 2; ++c)
            #pragma unroll
            for (int j = 0; j < 8; ++j)
                rs += bf16_f32((u16)va[c][j]);
        __syncthreads();
        #pragma unroll
        for (int c = 0; c < 2; ++c) {
            const int kb = kq * 2 + c;
            *reinterpret_cast<s16x8*>(lA + (kb * 64 + srow) * 8) = va[c];
            *reinterpret_cast<s16x8*>(lB + (kb * 64 + srow) * 8) = vb[c];
        }
        __syncthreads();
        #pragma unroll
        for (int ksub = 0; ksub < 2; ++ksub) {
            const int kb = (l >> 4) + ksub * 4;
            s16x8 af = *reinterpret_cast<const s16x8*>(lA + (kb * 64 + w * 16 + (l & 15)) * 8);
            #pragma unroll
            for (int nb = 0; nb < 4; ++nb) {
                if (nb < nfrag) {
                    s16x8 bf = *reinterpret_cast<const s16x8*>(lB + (kb * 64 + nb * 16 + (l & 15)) * 8);
                    acc[nb] = __builtin_amdgcn_mfma_f32_16x16x32_bf16(af, bf, acc[nb], 0, 0, 0);
                }
            }
        }
    }
    rs += __shfl_xor(rs, 1);
    rs += __shfl_xor(rs, 2);
    if (kq == 0) rinv[srow] = 1.0f / rs;
    __syncthreads();

    const int mbase = w * 16 + (l >> 4) * 4;
    #pragma unroll
    for (int nb = 0; nb < 4; ++nb) {
        if (nb >= nfrag) break;
        const int col = n0 + nb * 16 + (l & 15);
        #pragma unroll
        for (int r = 0; r < 4; ++r) {
            const float v = acc[nb][r] * rinv[mbase + r];
            ctxb[(size_t)(mt * 64 + mbase + r) * 768 + h * 96 + col] = cvt_bf16(v);
        }
    }
}

// ---------------------------------------------------------------------------
// L6 gates+ww (512 blocks): [0,256) gates+delta per batch; [256,512) ww per batch.
// (outproj moved OFF the critical path into the final launch — gates use ctx
//  directly via vg/gc, never rd_out.)
// ---------------------------------------------------------------------------
__global__ __launch_bounds__(256) void gatesww_kernel(
    const u16* __restrict__ ctxb,
    const float* __restrict__ cs, const float* __restrict__ wdta,
    const float* __restrict__ erase,
    const float* __restrict__ ugw, const float* __restrict__ fgw,
    const float* __restrict__ vg, const float* __restrict__ gc,
    const u16* __restrict__ E,
    float* __restrict__ delta, float* __restrict__ wwb)
{
    const int bid = blockIdx.x, t = threadIdx.x;
    if (bid < 256) {
        const int b = bid;
        __shared__ float red[8];
        float pu = 0.f, pf = 0.f;
        #pragma unroll
        for (int c = 0; c < 3; ++c) {
            const int i = t + c * 256;
            const float cv = cs[(size_t)b * 768 + i];
            const float xv = bf16_f32(ctxb[(size_t)b * 768 + i]);
            pu += cv * ugw[i] + xv * vg[i];
            pf += cv * fgw[i] + xv * vg[768 + i];
        }
        const int w = t >> 6, l = t & 63;
        #pragma unroll
        for (int off = 32; off > 0; off >>= 1) {
            pu += __shfl_xor(pu, off);
            pf += __shfl_xor(pf, off);
        }
        if (l == 0) { red[w] = pu; red[4 + w] = pf; }
        __syncthreads();
        const float ug = 1.0f / (1.0f + expf(-(red[0] + red[1] + red[2] + red[3] + gc[0])));
        const float fg = 1.0f / (1.0f + expf(-(red[4] + red[5] + red[6] + red[7] + gc[1])));
        #pragma unroll
        for (int c = 0; c < 3; ++c) {
            const int i = t + c * 256;
            delta[(size_t)b * 768 + i] = wdta[(size_t)b * 768 + i] * ug
                                       - erase[(size_t)b * 768 + i] * fg;
        }
    } else {
        // ww[b][m] = 0.125 * sum_h E[h][256+b][m] / rowsum(h, 256+b)
        const int b = bid - 256;
        __shared__ float linv8[8];
        const int w = t >> 6, l = t & 63;
        #pragma unroll
        for (int hh = 0; hh < 2; ++hh) {
            const int h = w * 2 + hh;
            const u16* row = E + ((size_t)h * 512 + 256 + b) * 512;
            float s = 0.f;
            #pragma unroll
            for (int c = 0; c < 8; ++c) s += bf16_f32(row[c * 64 + l]);
            #pragma unroll
            for (int off = 32; off > 0; off >>= 1) s += __shfl_xor(s, off);
            if (l == 0) linv8[h] = 1.0f / s;
        }
        __syncthreads();
        #pragma unroll
        for (int mm_ = 0; mm_ < 2; ++mm_) {
            const int m = t + mm_ * 256;
            float s = 0.f;
            #pragma unroll
            for (int h = 0; h < H_; ++h)
                s += bf16_f32(E[((size_t)h * 512 + 256 + b) * 512 + m]) * linv8[h];
            wwb[(size_t)b * 512 + m] = s * 0.125f;
        }
    }
}

// ---------------------------------------------------------------------------
// L7 final (16432 blocks): [0,48) out-projection -> rd_out (hides under the
// write stream); [48,16432) memory update (403 MB, NT stores).
// NOTE: everything this launch reads lives in d_ws or inputs (outwb is in d_ws)
// because the update blocks overwrite the whole mem_out region.
// ---------------------------------------------------------------------------
__global__ __launch_bounds__(256) void final_kernel(
    const u16* __restrict__ ctxb, const u16* __restrict__ outwb,
    const float* __restrict__ outb, float* __restrict__ rd_out,
    const float* __restrict__ mem, const float* __restrict__ wwb,
    const float* __restrict__ delta, float* __restrict__ mem_out)
{
    __shared__ u16 lA[8192], lB[8192];
    const int bid = blockIdx.x, t = threadIdx.x;
    if (bid < 48) {
        f32x4_t acc[4] = ACC_INIT;
        const int mt = bid / 12, nt = bid % 12;
        mm64b<64>(ctxb + (size_t)mt * 64 * 768, 768, outwb + (size_t)nt * 64 * 768, 768,
                  12, 63, lA, lB, acc, 4);
        epilogue_f32(acc, rd_out, 768, mt * 64, nt * 64, outb, 0, 4);
    } else {
        const int u = bid - 48;
        const int b  = u >> 6;            // 64 units per batch
        const int m0 = (u & 63) << 3;     // 8 rows per unit
        const f32x4_t* m4 = reinterpret_cast<const f32x4_t*>(mem);
        f32x4_t* o4 = reinterpret_cast<f32x4_t*>(mem_out + (size_t)b * 393216);
        const float* drow = delta + (size_t)b * 768;
        #pragma unroll
        for (int ph = 0; ph < 6; ++ph) {
            const int c = t + ph * 256;           // 0..1535 = 8 rows x 192 chunks
            const int m = m0 + c / 192;
            const int d4 = c % 192;
            const float w = wwb[(size_t)b * 512 + m];
            const f32x4_t dd = *reinterpret_cast<const f32x4_t*>(drow + d4 * 4);
            f32x4_t mm = m4[(size_t)m * 192 + d4];
            f32x4_t r = mm + w * dd;
            __builtin_nontemporal_store(r, &o4[(size_t)m * 192 + d4]);
        }
    }
}

// ---------------------------------------------------------------------------
extern "C" void kernel_launch(void* const* d_in, const int* in_sizes, int n_in,
                              void* d_out, int out_size, void* d_ws, size_t ws_size,
                              hipStream_t stream)
{
    const float* cs   = (const float*)d_in[0];
    const float* wdta = (const float*)d_in[1];
    const float* mem  = (const float*)d_in[2];
    const float* ipw  = (const float*)d_in[3];
    const float* ipb  = (const float*)d_in[4];
    const float* outw = (const float*)d_in[5];
    const float* outb = (const float*)d_in[6];
    const float* rw   = (const float*)d_in[7];
    const float* rb   = (const float*)d_in[8];
    const float* ww_w = (const float*)d_in[9];
    const float* ww_b = (const float*)d_in[10];
    const float* ew   = (const float*)d_in[11];
    const float* eb   = (const float*)d_in[12];
    const float* ugw  = (const float*)d_in[13];
    const float* ugb  = (const float*)d_in[14];
    const float* fgw  = (const float*)d_in[15];
    const float* fgb  = (const float*)d_in[16];

    float* rd_out  = (float*)d_out;              // read_data (B, D)
    float* mem_out = (float*)d_out + B_ * D_;    // updated_memory (B, M, D)

    // Scratch in mem_out region (dead until the final launch's update blocks;
    // the final launch reads ONLY inputs + d_ws). Offsets in f32 WORDS, %4==0.
    float* S0 = mem_out;
    u16*   memb    = (u16*)(S0 + 0);         // 512*768 bf16
    u16*   csb     = (u16*)(S0 + 196608);    // 256*768 bf16
    u16*   ipwb    = (u16*)(S0 + 294912);    // 2304*768 bf16
    u16*   rwb     = (u16*)(S0 + 1179648);   // 768*768 bf16
    u16*   wwwb    = (u16*)(S0 + 1474560);   // 768*768 bf16
    u16*   ewb     = (u16*)(S0 + 1769472);   // 768*768 bf16
    u16*   khb     = (u16*)(S0 + 2064384);   // 512*768 bf16
    u16*   vhT     = (u16*)(S0 + 2260992);   // 768*512 bf16
    u16*   rwkeysb = (u16*)(S0 + 2457600);   // 512*768 bf16
    u16*   qrwb    = (u16*)(S0 + 2654208);   // 512*768 bf16 (end 2850816 f)

    // d_ws (f32 words; all offsets %4==0). outwb lives HERE because the final
    // launch reads it while update overwrites mem_out.
    float* ws    = (float*)d_ws;
    float* erase = ws;                       // 196608 @ 0
    u16*   ctxb  = (u16*)(ws + 196608);      //  98304
    u16*   E     = (u16*)(ws + 294912);      // 1048576
    float* vg    =        ws + 1343488;      //   1536
    float* gc    =        ws + 1345024;      //     16
    float* delta =        ws + 1345040;      // 196608
    float* wwb   =        ws + 1541648;      // 131072
    u16*   outwb = (u16*)(ws + 1672720);     // 768*768 bf16 -> 294912 (end 1967632 f ≈ 7.9 MB)

    conv_kernel<<<2328, 256, 0, stream>>>(mem, cs, ipw, rw, ww_w, ew, outw, outb,
                                          ugw, ugb, fgw, fgb,
                                          memb, csb, ipwb, rwb, wwwb, ewb, outwb,
                                          vg, gc);
    stage1_kernel<<<336, 256, 0, stream>>>(memb, csb, ipwb, ipb, rwb, rb, wwwb, ww_b,
                                           ewb, eb, khb, vhT, rwkeysb, erase);
    stage2_kernel<<<96, 256, 0, stream>>>(rwkeysb, ipwb, ipb, qrwb);
    scores_kernel<<<dim3(64, 8), 256, 0, stream>>>(qrwb, khb, E);
    pv_kernel<<<dim3(4, 2, 8), 256, 0, stream>>>(E, vhT, ctxb);
    gatesww_kernel<<<512, 256, 0, stream>>>(ctxb, cs, wdta, erase, ugw, fgw, vg, gc,
                                            E, delta, wwb);
    final_kernel<<<16432, 256, 0, stream>>>(ctxb, outwb, outb, rd_out,
                                            mem, wwb, delta, mem_out);
}

// Round 12
// 139.020 us; speedup vs baseline: 3.5463x; 1.0153x over previous
//
#include <hip/hip_runtime.h>
#include <hip/hip_bf16.h>
#include <math.h>

// Problem constants
#define B_ 256
#define M_ 512
#define D_ 768
#define H_ 8
#define DH_ 96
#define C_ 768

typedef float  f32x4_t __attribute__((ext_vector_type(4)));
typedef short  s16x8   __attribute__((ext_vector_type(8)));
typedef unsigned short u16;

__device__ __forceinline__ u16 cvt_bf16(float f) {
    __hip_bfloat16 h = __float2bfloat16(f);     // HW cvt path (RNE)
    union { __hip_bfloat16 h; u16 u; } v; v.h = h;
    return v.u;
}
__device__ __forceinline__ float bf16_f32(u16 h) {
    union { unsigned int u; float f; } v; v.u = ((unsigned int)h) << 16;
    return v.f;
}

#define ACC_INIT {{0,0,0,0},{0,0,0,0},{0,0,0,0},{0,0,0,0}}
#define SCALE_ 0.10206207261596577f   // 1/sqrt(96)

// ---------------------------------------------------------------------------
// 64x64 bf16 MFMA GEMM core, software-pipelined: next k-step's global loads
// are issued right after the LDS-ready barrier so they overlap the MFMAs.
// tile = A(64xK) @ B(64xK)^T, both K-major bf16.
// ---------------------------------------------------------------------------
template<int BK>
__device__ __forceinline__ void mm64b(
    const u16* __restrict__ A, int lda, const u16* __restrict__ B, int ldb,
    int ksteps, int bRowClamp, u16* lA, u16* lB, f32x4_t* acc, int nfrag)
{
    constexpr int NL = BK / 32;
    const int t = threadIdx.x;
    const int srow = t >> 2, kq = t & 3;
    const int l = t & 63, w = t >> 6;
    const int brow = srow < bRowClamp ? srow : bRowClamp;

    s16x8 va[NL], vb[NL];
    #pragma unroll
    for (int c = 0; c < NL; ++c) {                 // preload k-step 0
        const int ko = (kq * NL + c) * 8;
        va[c] = *reinterpret_cast<const s16x8*>(A + (size_t)srow * lda + ko);
        vb[c] = *reinterpret_cast<const s16x8*>(B + (size_t)brow * ldb + ko);
    }

    for (int ks = 0; ks < ksteps; ++ks) {
        __syncthreads();                           // prev iter's frag reads done
        #pragma unroll
        for (int c = 0; c < NL; ++c) {
            const int kb = kq * NL + c;
            *reinterpret_cast<s16x8*>(lA + (kb * 64 + srow) * 8) = va[c];
            *reinterpret_cast<s16x8*>(lB + (kb * 64 + srow) * 8) = vb[c];
        }
        __syncthreads();
        if (ks + 1 < ksteps) {                     // prefetch: hides under MFMAs
            #pragma unroll
            for (int c = 0; c < NL; ++c) {
                const int ko = (ks + 1) * BK + (kq * NL + c) * 8;
                va[c] = *reinterpret_cast<const s16x8*>(A + (size_t)srow * lda + ko);
                vb[c] = *reinterpret_cast<const s16x8*>(B + (size_t)brow * ldb + ko);
            }
        }
        #pragma unroll
        for (int ksub = 0; ksub < NL; ++ksub) {
            const int kb = (l >> 4) + ksub * 4;
            s16x8 af = *reinterpret_cast<const s16x8*>(lA + (kb * 64 + w * 16 + (l & 15)) * 8);
            #pragma unroll
            for (int nb = 0; nb < 4; ++nb) {
                if (nb < nfrag) {
                    s16x8 bf = *reinterpret_cast<const s16x8*>(lB + (kb * 64 + nb * 16 + (l & 15)) * 8);
                    acc[nb] = __builtin_amdgcn_mfma_f32_16x16x32_bf16(af, bf, acc[nb], 0, 0, 0);
                }
            }
        }
    }
}

// C/D layout: col = lane&15, row = (lane>>4)*4 + reg (within wave's 16-row slice).
__device__ __forceinline__ void epilogue_f32(
    const f32x4_t* acc, float* out, int ldo, int m0, int n0,
    const float* bias, int act, int nfrag)
{
    const int t = threadIdx.x, l = t & 63, w = t >> 6;
    const int mbase = m0 + w * 16 + (l >> 4) * 4;
    #pragma unroll
    for (int nb = 0; nb < 4; ++nb) {
        if (nb >= nfrag) break;
        const int col = n0 + nb * 16 + (l & 15);
        const float bv = bias ? bias[col] : 0.0f;
        #pragma unroll
        for (int r = 0; r < 4; ++r) {
            float v = acc[nb][r] + bv;
            if (act) v = 1.0f / (1.0f + expf(-v));
            out[(size_t)(mbase + r) * ldo + col] = v;
        }
    }
}

__device__ __forceinline__ void epilogue_bf16(
    const f32x4_t* acc, u16* out, int ldo, int m0, int n0,
    const float* bias, int nfrag)
{
    const int t = threadIdx.x, l = t & 63, w = t >> 6;
    const int mbase = m0 + w * 16 + (l >> 4) * 4;
    #pragma unroll
    for (int nb = 0; nb < 4; ++nb) {
        if (nb >= nfrag) break;
        const int col = n0 + nb * 16 + (l & 15);
        const float bv = bias ? bias[col] : 0.0f;
        #pragma unroll
        for (int r = 0; r < 4; ++r)
            out[(size_t)(mbase + r) * ldo + col] = cvt_bf16(acc[nb][r] + bv);
    }
}

// ---------------------------------------------------------------------------
// L1 conv (2328 blocks): f32->bf16 conversions (2304) + vg/gc GEMV (24).
// ---------------------------------------------------------------------------
__global__ __launch_bounds__(256) void conv_kernel(
    const float* __restrict__ mem, const float* __restrict__ cs,
    const float* __restrict__ ipw, const float* __restrict__ rw,
    const float* __restrict__ www, const float* __restrict__ ew,
    const float* __restrict__ outw, const float* __restrict__ outb,
    const float* __restrict__ ugw, const float* __restrict__ ugb,
    const float* __restrict__ fgw, const float* __restrict__ fgb,
    u16* __restrict__ memb, u16* __restrict__ csb, u16* __restrict__ ipwb,
    u16* __restrict__ rwb, u16* __restrict__ wwwb, u16* __restrict__ ewb,
    u16* __restrict__ outwb, float* __restrict__ vg, float* __restrict__ gc)
{
    __shared__ float sred[256];
    const int bid = blockIdx.x, t = threadIdx.x;

    if (bid < 2304) {
        const float* src; u16* dst; int base;
        if      (bid < 192)  { src = mem;  dst = memb;  base = bid; }
        else if (bid < 288)  { src = cs;   dst = csb;   base = bid - 192; }
        else if (bid < 1152) { src = ipw;  dst = ipwb;  base = bid - 288; }
        else if (bid < 1440) { src = rw;   dst = rwb;   base = bid - 1152; }
        else if (bid < 1728) { src = www;  dst = wwwb;  base = bid - 1440; }
        else if (bid < 2016) { src = ew;   dst = ewb;   base = bid - 1728; }
        else                 { src = outw; dst = outwb; base = bid - 2016; }
        const size_t i = ((size_t)base * 256 + t) * 8;
        float4 x = *reinterpret_cast<const float4*>(src + i);
        float4 y = *reinterpret_cast<const float4*>(src + i + 4);
        s16x8 o;
        o[0]=cvt_bf16(x.x); o[1]=cvt_bf16(x.y); o[2]=cvt_bf16(x.z); o[3]=cvt_bf16(x.w);
        o[4]=cvt_bf16(y.x); o[5]=cvt_bf16(y.y); o[6]=cvt_bf16(y.z); o[7]=cvt_bf16(y.w);
        *reinterpret_cast<s16x8*>(dst + i) = o;
    } else {
        const int lid = bid - 2304;
        const int v = lid / 12, kt = lid % 12;
        const float* gw = v == 0 ? ugw : fgw;
        const int c = t & 63, g = t >> 6;
        const int col = kt * 64 + c;
        float acc = 0.f;
        #pragma unroll 4
        for (int i = 0; i < 192; ++i) {
            const int row = g * 192 + i;
            acc += outw[(size_t)row * 768 + col] * gw[768 + row];
        }
        sred[t] = acc;
        __syncthreads();
        if (g == 0)
            vg[v * 768 + col] = sred[c] + sred[64 + c] + sred[128 + c] + sred[192 + c];
        if (kt == 0) {
            __syncthreads();
            float cp = outb[t] * gw[768 + t] + outb[t + 256] * gw[768 + t + 256]
                     + outb[t + 512] * gw[768 + t + 512];
            sred[t] = cp; __syncthreads();
            #pragma unroll
            for (int off = 128; off > 0; off >>= 1) {
                if (t < off) sred[t] += sred[t + off];
                __syncthreads();
            }
            if (t == 0) gc[v] = sred[0] + (v == 0 ? ugb[0] : fgb[0]);
        }
    }
}

// ---------------------------------------------------------------------------
// L2 stage1 (336 blocks): kh+vhT (192), read keys (48), write keys (48), erase (48)
// ---------------------------------------------------------------------------
__global__ __launch_bounds__(256) void stage1_kernel(
    const u16* __restrict__ memb, const u16* __restrict__ csb,
    const u16* __restrict__ ipwb, const float* __restrict__ ipb,
    const u16* __restrict__ rwb, const float* __restrict__ rb,
    const u16* __restrict__ wwwb, const float* __restrict__ ww_b,
    const u16* __restrict__ ewb, const float* __restrict__ eb,
    u16* __restrict__ khb, u16* __restrict__ vhT,
    u16* __restrict__ rwkeysb, float* __restrict__ erase)
{
    __shared__ u16 lA[8192], lB[8192];
    f32x4_t acc[4] = ACC_INIT;
    const int bid = blockIdx.x;
    if (bid < 192) {
        const int mt = bid / 24, nt = bid % 24;
        mm64b<64>(memb + (size_t)mt * 64 * 768, 768,
                  ipwb + (size_t)768 * 768 + (size_t)nt * 64 * 768, 768,
                  12, 63, lA, lB, acc, 4);
        const int t = threadIdx.x, l = t & 63, w = t >> 6;
        const int mbase = mt * 64 + w * 16 + (l >> 4) * 4;
        if (nt < 12) {
            #pragma unroll
            for (int nb = 0; nb < 4; ++nb) {
                const int col = nt * 64 + nb * 16 + (l & 15);
                const float bv = ipb[768 + col];
                #pragma unroll
                for (int r = 0; r < 4; ++r)
                    khb[(size_t)(mbase + r) * 768 + col] = cvt_bf16(acc[nb][r] + bv);
            }
        } else {
            #pragma unroll
            for (int nb = 0; nb < 4; ++nb) {
                const int cg = (nt - 12) * 64 + nb * 16 + (l & 15);   // 0..767
                const int h = cg / 96, d = cg % 96;
                const float bv = ipb[1536 + cg];
                u16* dst = vhT + ((size_t)h * 96 + d) * 512;
                #pragma unroll
                for (int r = 0; r < 4; ++r)
                    dst[mbase + r] = cvt_bf16(acc[nb][r] + bv);
            }
        }
    } else if (bid < 240) {
        const int lid = bid - 192, mt = lid / 12, nt = lid % 12;
        mm64b<64>(csb + (size_t)mt * 64 * 768, 768, rwb + (size_t)nt * 64 * 768, 768,
                  12, 63, lA, lB, acc, 4);
        epilogue_bf16(acc, rwkeysb, 768, mt * 64, nt * 64, rb, 4);
    } else if (bid < 288) {
        const int lid = bid - 240, mt = lid / 12, nt = lid % 12;
        mm64b<64>(csb + (size_t)mt * 64 * 768, 768, wwwb + (size_t)nt * 64 * 768, 768,
                  12, 63, lA, lB, acc, 4);
        epilogue_bf16(acc, rwkeysb + (size_t)256 * 768, 768, mt * 64, nt * 64, ww_b, 4);
    } else {
        const int lid = bid - 288, mt = lid / 12, nt = lid % 12;
        mm64b<64>(csb + (size_t)mt * 64 * 768, 768, ewb + (size_t)nt * 64 * 768, 768,
                  12, 63, lA, lB, acc, 4);
        epilogue_f32(acc, erase, 768, mt * 64, nt * 64, eb, 1, 4);
    }
}

// ---------------------------------------------------------------------------
// L3 stage2 (96 blocks): qrw = rwkeys(512x768) @ wq^T + bq -> bf16
// ---------------------------------------------------------------------------
__global__ __launch_bounds__(256) void stage2_kernel(
    const u16* __restrict__ rwkeysb, const u16* __restrict__ ipwb,
    const float* __restrict__ ipb, u16* __restrict__ qrwb)
{
    __shared__ u16 lA[8192], lB[8192];
    f32x4_t acc[4] = ACC_INIT;
    const int mt = blockIdx.x / 12, nt = blockIdx.x % 12;
    mm64b<64>(rwkeysb + (size_t)mt * 64 * 768, 768, ipwb + (size_t)nt * 64 * 768, 768,
              12, 63, lA, lB, acc, 4);
    epilogue_bf16(acc, qrwb, 768, mt * 64, nt * 64, ipb, 4);
}

// ---------------------------------------------------------------------------
// L4 scores (grid (64,8)): E[h][q][m] = exp(min(q.k*scale,30)) bf16
// ---------------------------------------------------------------------------
__global__ __launch_bounds__(256) void scores_kernel(
    const u16* __restrict__ qrwb, const u16* __restrict__ khb, u16* __restrict__ E)
{
    __shared__ u16 lA[2048], lB[2048];
    f32x4_t acc[4] = ACC_INIT;
    const int h = blockIdx.y;
    const int mt = blockIdx.x >> 3, nt = blockIdx.x & 7;
    mm64b<32>(qrwb + (size_t)mt * 64 * 768 + h * 96, 768,
              khb + (size_t)nt * 64 * 768 + h * 96, 768, 3, 63, lA, lB, acc, 4);
    const int t = threadIdx.x, l = t & 63, w = t >> 6;
    const int mbase = mt * 64 + w * 16 + (l >> 4) * 4;     // q
    #pragma unroll
    for (int nb = 0; nb < 4; ++nb) {
        const int col = nt * 64 + nb * 16 + (l & 15);       // m
        #pragma unroll
        for (int r = 0; r < 4; ++r) {
            const float e = expf(fminf(acc[nb][r] * SCALE_, 30.0f));
            E[((size_t)h * 512 + mbase + r) * 512 + col] = cvt_bf16(e);
        }
    }
}

// ---------------------------------------------------------------------------
// L5 PV (grid (4,2,8)): ctx = (E_rows/rowsum) @ vhT^T -> ctxb bf16.
// Software-pipelined like mm64b; row sums accumulated at staging time.
// ---------------------------------------------------------------------------
__global__ __launch_bounds__(256) void pv_kernel(
    const u16* __restrict__ E, const u16* __restrict__ vhT, u16* __restrict__ ctxb)
{
    __shared__ u16 lA[8192], lB[8192];
    __shared__ float rinv[64];
    f32x4_t acc[4] = ACC_INIT;
    const int h = blockIdx.z, mt = blockIdx.x, nt = blockIdx.y;
    const int n0 = nt * 64;
    const int nfrag = nt == 0 ? 4 : 2;
    const int bclamp = nt == 0 ? 63 : 31;

    const u16* A  = E + ((size_t)h * 512 + mt * 64) * 512;
    const u16* Bv = vhT + ((size_t)h * 96 + n0) * 512;

    const int t = threadIdx.x;
    const int srow = t >> 2, kq = t & 3;
    const int l = t & 63, w = t >> 6;
    const int brow = srow < bclamp ? srow : bclamp;

    s16x8 va[2], vb[2];
    #pragma unroll
    for (int c = 0; c < 2; ++c) {                  // preload ks=0
        const int ko = (kq * 2 + c) * 8;
        va[c] = *reinterpret_cast<const s16x8*>(A + (size_t)srow * 512 + ko);
        vb[c] = *reinterpret_cast<const s16x8*>(Bv + (size_t)brow * 512 + ko);
    }

    float rs = 0.f;
    for (int ks = 0; ks < 8; ++ks) {
        __syncthreads();
        #pragma unroll
        for (int c = 0; c < 2; ++c) {
            const int kb = kq * 2 + c;
            *reinterpret_cast<s16x8*>(lA + (kb * 64 + srow) * 8) = va[c];
            *reinterpret_cast<s16x8*>(lB + (kb * 64 + srow) * 8) = vb[c];
        }
        #pragma unroll
        for (int c = 0; c < 2; ++c)                // row-sum on staged values
            #pragma unroll
            for (int j = 0; j < 8; ++j)
                rs += bf16_f32((u16)va[c][j]);
        __syncthreads();
        if (ks + 1 < 8) {                          // prefetch hides under MFMAs
            #pragma unroll
            for (int c = 0; c < 2; ++c) {
                const int ko = (ks + 1) * 64 + (kq * 2 + c) * 8;
                va[c] = *reinterpret_cast<const s16x8*>(A + (size_t)srow * 512 + ko);
                vb[c] = *reinterpret_cast<const s16x8*>(Bv + (size_t)brow * 512 + ko);
            }
        }
        #pragma unroll
        for (int ksub = 0; ksub < 2; ++ksub) {
            const int kb = (l >> 4) + ksub * 4;
            s16x8 af = *reinterpret_cast<const s16x8*>(lA + (kb * 64 + w * 16 + (l & 15)) * 8);
            #pragma unroll
            for (int nb = 0; nb < 4; ++nb) {
                if (nb < nfrag) {
                    s16x8 bf = *reinterpret_cast<const s16x8*>(lB + (kb * 64 + nb * 16 + (l & 15)) * 8);
                    acc[nb] = __builtin_amdgcn_mfma_f32_16x16x32_bf16(af, bf, acc[nb], 0, 0, 0);
                }
            }
        }
    }
    rs += __shfl_xor(rs, 1);
    rs += __shfl_xor(rs, 2);
    if (kq == 0) rinv[srow] = 1.0f / rs;
    __syncthreads();

    const int mbase = w * 16 + (l >> 4) * 4;
    #pragma unroll
    for (int nb = 0; nb < 4; ++nb) {
        if (nb >= nfrag) break;
        const int col = n0 + nb * 16 + (l & 15);
        #pragma unroll
        for (int r = 0; r < 4; ++r) {
            const float v = acc[nb][r] * rinv[mbase + r];
            ctxb[(size_t)(mt * 64 + mbase + r) * 768 + h * 96 + col] = cvt_bf16(v);
        }
    }
}

// ---------------------------------------------------------------------------
// L6 gates+ww (512 blocks): [0,256) gates+delta per batch; [256,512) ww per batch.
// ---------------------------------------------------------------------------
__global__ __launch_bounds__(256) void gatesww_kernel(
    const u16* __restrict__ ctxb,
    const float* __restrict__ cs, const float* __restrict__ wdta,
    const float* __restrict__ erase,
    const float* __restrict__ ugw, const float* __restrict__ fgw,
    const float* __restrict__ vg, const float* __restrict__ gc,
    const u16* __restrict__ E,
    float* __restrict__ delta, float* __restrict__ wwb)
{
    const int bid = blockIdx.x, t = threadIdx.x;
    if (bid < 256) {
        const int b = bid;
        __shared__ float red[8];
        float pu = 0.f, pf = 0.f;
        #pragma unroll
        for (int c = 0; c < 3; ++c) {
            const int i = t + c * 256;
            const float cv = cs[(size_t)b * 768 + i];
            const float xv = bf16_f32(ctxb[(size_t)b * 768 + i]);
            pu += cv * ugw[i] + xv * vg[i];
            pf += cv * fgw[i] + xv * vg[768 + i];
        }
        const int w = t >> 6, l = t & 63;
        #pragma unroll
        for (int off = 32; off > 0; off >>= 1) {
            pu += __shfl_xor(pu, off);
            pf += __shfl_xor(pf, off);
        }
        if (l == 0) { red[w] = pu; red[4 + w] = pf; }
        __syncthreads();
        const float ug = 1.0f / (1.0f + expf(-(red[0] + red[1] + red[2] + red[3] + gc[0])));
        const float fg = 1.0f / (1.0f + expf(-(red[4] + red[5] + red[6] + red[7] + gc[1])));
        #pragma unroll
        for (int c = 0; c < 3; ++c) {
            const int i = t + c * 256;
            delta[(size_t)b * 768 + i] = wdta[(size_t)b * 768 + i] * ug
                                       - erase[(size_t)b * 768 + i] * fg;
        }
    } else {
        // ww[b][m] = 0.125 * sum_h E[h][256+b][m] / rowsum(h, 256+b)
        const int b = bid - 256;
        __shared__ float linv8[8];
        const int w = t >> 6, l = t & 63;
        #pragma unroll
        for (int hh = 0; hh < 2; ++hh) {
            const int h = w * 2 + hh;
            const u16* row = E + ((size_t)h * 512 + 256 + b) * 512;
            float s = 0.f;
            #pragma unroll
            for (int c = 0; c < 8; ++c) s += bf16_f32(row[c * 64 + l]);
            #pragma unroll
            for (int off = 32; off > 0; off >>= 1) s += __shfl_xor(s, off);
            if (l == 0) linv8[h] = 1.0f / s;
        }
        __syncthreads();
        #pragma unroll
        for (int mm_ = 0; mm_ < 2; ++mm_) {
            const int m = t + mm_ * 256;
            float s = 0.f;
            #pragma unroll
            for (int h = 0; h < H_; ++h)
                s += bf16_f32(E[((size_t)h * 512 + 256 + b) * 512 + m]) * linv8[h];
            wwb[(size_t)b * 512 + m] = s * 0.125f;
        }
    }
}

// ---------------------------------------------------------------------------
// L7 final (16432 blocks): [0,48) out-projection -> rd_out (hides under the
// write stream); [48,16432) memory update (403 MB, NT stores).
// ---------------------------------------------------------------------------
__global__ __launch_bounds__(256) void final_kernel(
    const u16* __restrict__ ctxb, const u16* __restrict__ outwb,
    const float* __restrict__ outb, float* __restrict__ rd_out,
    const float* __restrict__ mem, const float* __restrict__ wwb,
    const float* __restrict__ delta, float* __restrict__ mem_out)
{
    __shared__ u16 lA[8192], lB[8192];
    const int bid = blockIdx.x, t = threadIdx.x;
    if (bid < 48) {
        f32x4_t acc[4] = ACC_INIT;
        const int mt = bid / 12, nt = bid % 12;
        mm64b<64>(ctxb + (size_t)mt * 64 * 768, 768, outwb + (size_t)nt * 64 * 768, 768,
                  12, 63, lA, lB, acc, 4);
        epilogue_f32(acc, rd_out, 768, mt * 64, nt * 64, outb, 0, 4);
    } else {
        const int u = bid - 48;
        const int b  = u >> 6;            // 64 units per batch
        const int m0 = (u & 63) << 3;     // 8 rows per unit
        const f32x4_t* m4 = reinterpret_cast<const f32x4_t*>(mem);
        f32x4_t* o4 = reinterpret_cast<f32x4_t*>(mem_out + (size_t)b * 393216);
        const float* drow = delta + (size_t)b * 768;
        #pragma unroll
        for (int ph = 0; ph < 6; ++ph) {
            const int c = t + ph * 256;           // 0..1535 = 8 rows x 192 chunks
            const int m = m0 + c / 192;
            const int d4 = c % 192;
            const float w = wwb[(size_t)b * 512 + m];
            const f32x4_t dd = *reinterpret_cast<const f32x4_t*>(drow + d4 * 4);
            f32x4_t mm = m4[(size_t)m * 192 + d4];
            f32x4_t r = mm + w * dd;
            __builtin_nontemporal_store(r, &o4[(size_t)m * 192 + d4]);
        }
    }
}

// ---------------------------------------------------------------------------
extern "C" void kernel_launch(void* const* d_in, const int* in_sizes, int n_in,
                              void* d_out, int out_size, void* d_ws, size_t ws_size,
                              hipStream_t stream)
{
    const float* cs   = (const float*)d_in[0];
    const float* wdta = (const float*)d_in[1];
    const float* mem  = (const float*)d_in[2];
    const float* ipw  = (const float*)d_in[3];
    const float* ipb  = (const float*)d_in[4];
    const float* outw = (const float*)d_in[5];
    const float* outb = (const float*)d_in[6];
    const float* rw   = (const float*)d_in[7];
    const float* rb   = (const float*)d_in[8];
    const float* ww_w = (const float*)d_in[9];
    const float* ww_b = (const float*)d_in[10];
    const float* ew   = (const float*)d_in[11];
    const float* eb   = (const float*)d_in[12];
    const float* ugw  = (const float*)d_in[13];
    const float* ugb  = (const float*)d_in[14];
    const float* fgw  = (const float*)d_in[15];
    const float* fgb  = (const float*)d_in[16];

    float* rd_out  = (float*)d_out;              // read_data (B, D)
    float* mem_out = (float*)d_out + B_ * D_;    // updated_memory (B, M, D)

    // Scratch in mem_out region (dead until the final launch's update blocks;
    // the final launch reads ONLY inputs + d_ws). Offsets in f32 WORDS, %4==0.
    float* S0 = mem_out;
    u16*   memb    = (u16*)(S0 + 0);         // 512*768 bf16
    u16*   csb     = (u16*)(S0 + 196608);    // 256*768 bf16
    u16*   ipwb    = (u16*)(S0 + 294912);    // 2304*768 bf16
    u16*   rwb     = (u16*)(S0 + 1179648);   // 768*768 bf16
    u16*   wwwb    = (u16*)(S0 + 1474560);   // 768*768 bf16
    u16*   ewb     = (u16*)(S0 + 1769472);   // 768*768 bf16
    u16*   khb     = (u16*)(S0 + 2064384);   // 512*768 bf16
    u16*   vhT     = (u16*)(S0 + 2260992);   // 768*512 bf16
    u16*   rwkeysb = (u16*)(S0 + 2457600);   // 512*768 bf16
    u16*   qrwb    = (u16*)(S0 + 2654208);   // 512*768 bf16 (end 2850816 f)

    // d_ws (f32 words; all offsets %4==0). outwb lives HERE because the final
    // launch reads it while update overwrites mem_out.
    float* ws    = (float*)d_ws;
    float* erase = ws;                       // 196608 @ 0
    u16*   ctxb  = (u16*)(ws + 196608);      //  98304
    u16*   E     = (u16*)(ws + 294912);      // 1048576
    float* vg    =        ws + 1343488;      //   1536
    float* gc    =        ws + 1345024;      //     16
    float* delta =        ws + 1345040;      // 196608
    float* wwb   =        ws + 1541648;      // 131072
    u16*   outwb = (u16*)(ws + 1672720);     // 768*768 bf16 -> 294912 (end 1967632 f)

    conv_kernel<<<2328, 256, 0, stream>>>(mem, cs, ipw, rw, ww_w, ew, outw, outb,
                                          ugw, ugb, fgw, fgb,
                                          memb, csb, ipwb, rwb, wwwb, ewb, outwb,
                                          vg, gc);
    stage1_kernel<<<336, 256, 0, stream>>>(memb, csb, ipwb, ipb, rwb, rb, wwwb, ww_b,
                                           ewb, eb, khb, vhT, rwkeysb, erase);
    stage2_kernel<<<96, 256, 0, stream>>>(rwkeysb, ipwb, ipb, qrwb);
    scores_kernel<<<dim3(64, 8), 256, 0, stream>>>(qrwb, khb, E);
    pv_kernel<<<dim3(4, 2, 8), 256, 0, stream>>>(E, vhT, ctxb);
    gatesww_kernel<<<512, 256, 0, stream>>>(ctxb, cs, wdta, erase, ugw, fgw, vg, gc,
                                            E, delta, wwb);
    final_kernel<<<16432, 256, 0, stream>>>(ctxb, outwb, outb, rd_out,
                                            mem, wwb, delta, mem_out);
}